// Round 1
// baseline (2791.504 us; speedup 1.0000x reference)
//
#include <hip/hip_runtime.h>

#define T_   128
#define B_   256
#define C_   512
#define H_   512
#define L_   26
#define NCLS 6736
#define NPAD 6784   // 53*128, padded N for final GEMM

typedef __attribute__((ext_vector_type(8))) short short8;
typedef __attribute__((ext_vector_type(4))) float f32x4;

__device__ __forceinline__ unsigned short f2b(float f) {
    union { float f; unsigned int u; } v; v.f = f;
    unsigned int r = (v.u + 0x7fffu + ((v.u >> 16) & 1u)) >> 16;
    return (unsigned short)r;
}
__device__ __forceinline__ float b2f(unsigned short u) {
    union { unsigned int u; float f; } v; v.u = ((unsigned int)u) << 16;
    return v.f;
}
__device__ __forceinline__ float tanh_fast(float x) {
    float e = __expf(2.f * x);
    return 1.f - 2.f / (e + 1.f);
}
__device__ __forceinline__ float sigm(float x) {
    return 1.f / (1.f + __expf(-x));
}
__device__ __forceinline__ void llds16(const unsigned short* g, unsigned short* l) {
    __builtin_amdgcn_global_load_lds(
        (const __attribute__((address_space(1))) void*)g,
        (__attribute__((address_space(3))) void*)l, 16, 0, 0);
}

// ---------------- prep: casts + zero-init h ----------------
__global__ __launch_bounds__(256) void prep_kernel(
    const float* __restrict__ feats, const float* __restrict__ W_i2h,
    const float* __restrict__ W_gen,
    unsigned short* __restrict__ feats16, unsigned short* __restrict__ wi2h16,
    unsigned short* __restrict__ wgen16, float* __restrict__ h)
{
    size_t idx = (size_t)blockIdx.x * 256 + threadIdx.x;   // 16,777,216 total
    feats16[idx] = f2b(feats[idx]);
    if (idx < (size_t)H_ * C_) wi2h16[idx] = f2b(W_i2h[idx]);
    if (idx < (size_t)NPAD * H_)
        wgen16[idx] = (idx < (size_t)NCLS * H_) ? f2b(W_gen[idx]) : (unsigned short)0;
    if (idx < (size_t)B_ * H_) h[idx] = 0.f;
}

// ---------------- bf16 MFMA GEMM, C = A @ B^T (+bias) ----------------
// A [M,K] bf16 row-major, B [N,K] bf16 row-major. 128x128 tile, BK=32,
// 256 thr = 4 waves (2x2 of 64x64), 16x16x32 MFMA, global_load_lds width 16.
template<int OUTMODE>   // 0: bf16 out (ld=N, no bias)  1: f32 out + bias + col<ncols guard (ld=ncols)
__global__ __launch_bounds__(256) void gemm_bt(
    const unsigned short* __restrict__ A, const unsigned short* __restrict__ B,
    void* __restrict__ outp, const float* __restrict__ bias,
    int M, int N, int K, int ncols)
{
    __shared__ unsigned short As[128 * 32];
    __shared__ unsigned short Bs[128 * 32];
    const int tid = threadIdx.x;
    const int lane = tid & 63;
    const int m0 = blockIdx.y * 128;
    const int n0 = blockIdx.x * 128;
    const int wv = tid >> 6;
    const int wm = (wv >> 1) * 64;
    const int wn = (wv & 1) * 64;

    f32x4 acc[4][4];
#pragma unroll
    for (int i = 0; i < 4; i++)
#pragma unroll
        for (int j = 0; j < 4; j++) acc[i][j] = (f32x4)0.f;

    for (int k0 = 0; k0 < K; k0 += 32) {
        __syncthreads();
#pragma unroll
        for (int is = 0; is < 2; ++is) {
            int c = is * 256 + tid;          // 16B chunk id: row=c>>2, col8=(c&3)*8
            int row = c >> 2, col = (c & 3) * 8;
            llds16(A + (size_t)(m0 + row) * K + k0 + col, &As[c * 8]);
            llds16(B + (size_t)(n0 + row) * K + k0 + col, &Bs[c * 8]);
        }
        __syncthreads();   // compiler drains vmcnt before barrier
        short8 af[4], bf[4];
#pragma unroll
        for (int t = 0; t < 4; t++) {
            af[t] = *(const short8*)&As[(wm + t * 16 + (lane & 15)) * 32 + (lane >> 4) * 8];
            bf[t] = *(const short8*)&Bs[(wn + t * 16 + (lane & 15)) * 32 + (lane >> 4) * 8];
        }
#pragma unroll
        for (int i = 0; i < 4; i++)
#pragma unroll
            for (int j = 0; j < 4; j++)
                acc[i][j] = __builtin_amdgcn_mfma_f32_16x16x32_bf16(af[i], bf[j], acc[i][j], 0, 0, 0);
    }

    // C/D layout: col = lane&15, row = (lane>>4)*4 + r  [verified m89/m91]
    const int cr = (lane >> 4) * 4;
    const int cc = lane & 15;
    if constexpr (OUTMODE == 0) {
        unsigned short* o = (unsigned short*)outp;
#pragma unroll
        for (int i = 0; i < 4; i++)
#pragma unroll
            for (int j = 0; j < 4; j++) {
                int col = n0 + wn + j * 16 + cc;
#pragma unroll
                for (int r = 0; r < 4; r++) {
                    int row = m0 + wm + i * 16 + cr + r;
                    o[(size_t)row * N + col] = f2b(acc[i][j][r]);
                }
            }
    } else {
        float* o = (float*)outp;
#pragma unroll
        for (int j = 0; j < 4; j++) {
            int col = n0 + wn + j * 16 + cc;
            if (col < ncols) {
                float bv = bias[col];
#pragma unroll
                for (int i = 0; i < 4; i++)
#pragma unroll
                    for (int r = 0; r < 4; r++) {
                        int row = m0 + wm + i * 16 + cr + r;
                        o[(size_t)row * ncols + col] = acc[i][j][r] + bv;
                    }
            }
        }
    }
}

// ---------------- fp32 tiled GEMM: O = A @ W^T + b, N-concat of 2 outputs ----
// BM=64, BN=32, BK=16, 256 thr, micro 4x2. A [M,K], W rows [n,K].
__global__ __launch_bounds__(256) void gemm_f32(
    const float* __restrict__ A, int K,
    const float* __restrict__ W0, const float* __restrict__ b0,
    float* __restrict__ O0, int N0, int ldo0,
    const float* __restrict__ W1, const float* __restrict__ b1,
    float* __restrict__ O1, int ldo1)
{
    __shared__ float As[16][68];   // [k][m], padded: 68*4B = 17x16B (aligned, low-conflict)
    __shared__ float Bs[16][36];   // [k][n]
    const int tid = threadIdx.x;
    const int m0 = blockIdx.y * 64;
    const int ng = blockIdx.x * 32;

    const float* W; const float* bb; float* O; int no, ldo;
    if (ng < N0) { W = W0; bb = b0; O = O0; no = ng; ldo = ldo0; }
    else         { W = W1; bb = b1; O = O1; no = ng - N0; ldo = ldo1; }

    const int ty = tid >> 4, tx = tid & 15;
    float acc[4][2] = {};

    for (int k0 = 0; k0 < K; k0 += 16) {
        __syncthreads();
        {
            int row = tid >> 2, kq = (tid & 3) * 4;
            const float4 v = *(const float4*)(A + (size_t)(m0 + row) * K + k0 + kq);
            As[kq + 0][row] = v.x; As[kq + 1][row] = v.y;
            As[kq + 2][row] = v.z; As[kq + 3][row] = v.w;
        }
        if (tid < 128) {
            int row = tid >> 2, kq = (tid & 3) * 4;
            const float4 v = *(const float4*)(W + (size_t)(no + row) * K + k0 + kq);
            Bs[kq + 0][row] = v.x; Bs[kq + 1][row] = v.y;
            Bs[kq + 2][row] = v.z; Bs[kq + 3][row] = v.w;
        }
        __syncthreads();
#pragma unroll
        for (int k = 0; k < 16; k++) {
            const float4 av = *(const float4*)&As[k][ty * 4];
            const float2 bv = *(const float2*)&Bs[k][tx * 2];
            float am[4] = {av.x, av.y, av.z, av.w};
#pragma unroll
            for (int i = 0; i < 4; i++) {
                acc[i][0] += am[i] * bv.x;
                acc[i][1] += am[i] * bv.y;
            }
        }
    }
#pragma unroll
    for (int j = 0; j < 2; j++) {
        int n = no + tx * 2 + j;
        float bvv = bb[n];
#pragma unroll
        for (int i = 0; i < 4; i++)
            O[(size_t)(m0 + ty * 4 + i) * ldo + n] = acc[i][j] + bvv;
    }
}

// ---------------- attention step: e -> softmax(T) -> context, one block per b ----
__global__ __launch_bounds__(256) void attn_step(
    const unsigned short* __restrict__ fp,      // [T,B,H] bf16 feats_proj
    const unsigned short* __restrict__ feats16, // [T,B,C] bf16
    const float* __restrict__ hp,               // [B,H]
    const float* __restrict__ wscore,           // [H]
    float* __restrict__ ctx)                    // [B,C]
{
    const int b = blockIdx.x;
    const int tid = threadIdx.x, lane = tid & 63, wv = tid >> 6;
    __shared__ float se[T_];

    float hpr[8], wsr[8];
    {
        const float* hb = hp + b * H_ + lane * 8;
        const float* wb = wscore + lane * 8;
#pragma unroll
        for (int i = 0; i < 8; i++) { hpr[i] = hb[i]; wsr[i] = wb[i]; }
    }
    for (int t = wv; t < T_; t += 4) {
        const unsigned short* fr = fp + ((size_t)t * B_ + b) * H_ + lane * 8;
        short8 v = *(const short8*)fr;
        float p = 0.f;
#pragma unroll
        for (int i = 0; i < 8; i++) {
            float x = b2f((unsigned short)v[i]) + hpr[i];
            p += wsr[i] * tanh_fast(x);
        }
#pragma unroll
        for (int off = 32; off > 0; off >>= 1) p += __shfl_xor(p, off, 64);
        if (lane == 0) se[t] = p;
    }
    __syncthreads();
    if (wv == 0) {
        float v0 = se[lane], v1 = se[lane + 64];
        float mx = fmaxf(v0, v1);
#pragma unroll
        for (int off = 32; off > 0; off >>= 1) mx = fmaxf(mx, __shfl_xor(mx, off, 64));
        float e0 = __expf(v0 - mx), e1 = __expf(v1 - mx);
        float s = e0 + e1;
#pragma unroll
        for (int off = 32; off > 0; off >>= 1) s += __shfl_xor(s, off, 64);
        float inv = 1.f / s;
        se[lane] = e0 * inv; se[lane + 64] = e1 * inv;
    }
    __syncthreads();
    float a0 = 0.f, a1 = 0.f;
    const unsigned short* fb = feats16 + (size_t)b * C_ + tid * 2;
    for (int t = 0; t < T_; t++) {
        float al = se[t];
        unsigned int u = *(const unsigned int*)(fb + (size_t)t * B_ * C_);
        a0 += al * b2f((unsigned short)(u & 0xffffu));
        a1 += al * b2f((unsigned short)(u >> 16));
    }
    ctx[b * C_ + tid * 2]     = a0;
    ctx[b * C_ + tid * 2 + 1] = a1;
}

// ---------------- GRU gates + h update + out_h (bf16) write ----------------
__global__ __launch_bounds__(256) void gru_gate(
    const float* __restrict__ gi, const float* __restrict__ gh,
    float* __restrict__ h, unsigned short* __restrict__ outH, int step)
{
    int idx = blockIdx.x * 256 + threadIdx.x;   // B*H = 131072
    int b = idx >> 9, j = idx & 511;
    const float* gib = gi + (size_t)b * 1536;
    const float* ghb = gh + (size_t)b * 1536;
    float ir = gib[j], iz = gib[512 + j], inn = gib[1024 + j];
    float hr = ghb[j], hz = ghb[512 + j], hn = ghb[1024 + j];
    float r = sigm(ir + hr);
    float z = sigm(iz + hz);
    float n = tanh_fast(inn + r * hn);
    float hnew = (1.f - z) * n + z * h[idx];
    h[idx] = hnew;
    outH[((size_t)b * L_ + step) * H_ + j] = f2b(hnew);
}

extern "C" void kernel_launch(void* const* d_in, const int* in_sizes, int n_in,
                              void* d_out, int out_size, void* d_ws, size_t ws_size,
                              hipStream_t stream)
{
    const float* feats   = (const float*)d_in[0];
    const float* W_i2h   = (const float*)d_in[2];
    const float* W_h2h   = (const float*)d_in[3];
    const float* b_h2h   = (const float*)d_in[4];
    const float* W_score = (const float*)d_in[5];
    const float* W_ih    = (const float*)d_in[6];
    const float* W_hh    = (const float*)d_in[7];
    const float* b_ih    = (const float*)d_in[8];
    const float* b_hh    = (const float*)d_in[9];
    const float* W_gen   = (const float*)d_in[10];
    const float* b_gen   = (const float*)d_in[11];

    char* ws = (char*)d_ws;
    size_t off = 0;
    auto alloc = [&](size_t bytes) {
        void* p = ws + off; off += (bytes + 255) & ~(size_t)255; return p;
    };
    unsigned short* feats16 = (unsigned short*)alloc((size_t)T_ * B_ * C_ * 2);
    unsigned short* fp16    = (unsigned short*)alloc((size_t)T_ * B_ * H_ * 2);
    unsigned short* wgen16  = (unsigned short*)alloc((size_t)NPAD * H_ * 2);
    unsigned short* wi2h16  = (unsigned short*)alloc((size_t)H_ * C_ * 2);
    unsigned short* outH16  = (unsigned short*)alloc((size_t)B_ * L_ * H_ * 2);
    float* h   = (float*)alloc((size_t)B_ * H_ * 4);
    float* hp  = (float*)alloc((size_t)B_ * H_ * 4);
    float* gh  = (float*)alloc((size_t)B_ * 1536 * 4);
    float* ctx = (float*)alloc((size_t)B_ * C_ * 4);
    float* gi  = (float*)alloc((size_t)B_ * 1536 * 4);

    // prep: bf16 casts + zero h  (grid covers T*B*C = 16,777,216)
    prep_kernel<<<dim3((T_ * B_ * C_) / 256), 256, 0, stream>>>(
        feats, W_i2h, W_gen, feats16, wi2h16, wgen16, h);

    // feats_proj = feats @ W_i2h^T  -> bf16 [T*B, H]
    gemm_bt<0><<<dim3(H_ / 128, (T_ * B_) / 128), 256, 0, stream>>>(
        feats16, wi2h16, fp16, nullptr, T_ * B_, H_, C_, 0);

    for (int s = 0; s < L_; s++) {
        // [hp | gh] = h @ [W_h2h; W_hh]^T + bias   (N = 512 + 1536 = 2048)
        gemm_f32<<<dim3(2048 / 32, B_ / 64), 256, 0, stream>>>(
            h, H_, W_h2h, b_h2h, hp, 512, 512, W_hh, b_hh, gh, 1536);
        // e -> softmax -> context
        attn_step<<<dim3(B_), 256, 0, stream>>>(fp16, feats16, hp, W_score, ctx);
        // gi = context @ W_ih^T + b_ih   (N = 1536)
        gemm_f32<<<dim3(1536 / 32, B_ / 64), 256, 0, stream>>>(
            ctx, C_, W_ih, b_ih, gi, 1536, 1536, W_ih, b_ih, gi, 1536);
        // gates + h update + out_h write
        gru_gate<<<dim3((B_ * H_) / 256), 256, 0, stream>>>(gi, gh, h, outH16, s);
    }

    // probs = out_h @ W_gen^T + b_gen   (N padded 6784, store guard col < 6736)
    gemm_bt<1><<<dim3(NPAD / 128, (B_ * L_) / 128), 256, 0, stream>>>(
        outH16, wgen16, d_out, b_gen, B_ * L_, NPAD, H_, NCLS);
}

// Round 2
// 1325.342 us; speedup vs baseline: 2.1063x; 2.1063x over previous
//
#include <hip/hip_runtime.h>

#define T_   128
#define B_   256
#define C_   512
#define H_   512
#define L_   26
#define NCLS 6736
#define NPAD 6784   // 53*128, padded N for final GEMM

typedef __attribute__((ext_vector_type(8))) short short8;
typedef __attribute__((ext_vector_type(4))) float f32x4;

__device__ __forceinline__ unsigned short f2b(float f) {
    union { float f; unsigned int u; } v; v.f = f;
    unsigned int r = (v.u + 0x7fffu + ((v.u >> 16) & 1u)) >> 16;
    return (unsigned short)r;
}
__device__ __forceinline__ float b2f(unsigned short u) {
    union { unsigned int u; float f; } v; v.u = ((unsigned int)u) << 16;
    return v.f;
}
__device__ __forceinline__ float tanh_fast(float x) {
    float e = __expf(2.f * x);
    return 1.f - 2.f / (e + 1.f);
}
__device__ __forceinline__ float sigm(float x) {
    return 1.f / (1.f + __expf(-x));
}
__device__ __forceinline__ void llds16(const unsigned short* g, unsigned short* l) {
    __builtin_amdgcn_global_load_lds(
        (const __attribute__((address_space(1))) void*)g,
        (__attribute__((address_space(3))) void*)l, 16, 0, 0);
}

// ---------------- prep: casts + zero-init h ----------------
__global__ __launch_bounds__(256) void prep_kernel(
    const float* __restrict__ feats, const float* __restrict__ W_i2h,
    const float* __restrict__ W_gen, const float* __restrict__ W_h2h,
    const float* __restrict__ W_hh, const float* __restrict__ W_ih,
    unsigned short* __restrict__ feats16, unsigned short* __restrict__ wi2h16,
    unsigned short* __restrict__ wgen16, unsigned short* __restrict__ w1_16,
    unsigned short* __restrict__ wih16,
    float* __restrict__ h32, unsigned short* __restrict__ h16)
{
    size_t idx = (size_t)blockIdx.x * 256 + threadIdx.x;   // 16,777,216 total
    feats16[idx] = f2b(feats[idx]);
    if (idx < (size_t)H_ * C_) wi2h16[idx] = f2b(W_i2h[idx]);
    if (idx < (size_t)NPAD * H_)
        wgen16[idx] = (idx < (size_t)NCLS * H_) ? f2b(W_gen[idx]) : (unsigned short)0;
    if (idx < (size_t)2048 * 512)
        w1_16[idx] = f2b(idx < 262144 ? W_h2h[idx] : W_hh[idx - 262144]);
    if (idx < (size_t)1536 * 512) wih16[idx] = f2b(W_ih[idx]);
    if (idx < (size_t)B_ * H_) { h32[idx] = 0.f; h16[idx] = 0; }
}

// ---------------- bf16 MFMA GEMM, C = A @ B^T (+bias), XCD swizzle ----------------
template<int OUTMODE>   // 0: bf16 out (ld=N)  1: f32 out + bias + col<ncols guard (ld=ncols)
__global__ __launch_bounds__(256) void gemm_bt(
    const unsigned short* __restrict__ A, const unsigned short* __restrict__ B,
    void* __restrict__ outp, const float* __restrict__ bias,
    int M, int N, int K, int ncols)
{
    __shared__ unsigned short As[128 * 32];
    __shared__ unsigned short Bs[128 * 32];
    const int tid = threadIdx.x;
    const int lane = tid & 63;

    // GROUP_M=8 swizzle: 8 consecutive blocks (-> 8 XCDs) share one B-tile (n0),
    // and each XCD keeps re-hitting its own A-row tile in its L2.
    const int gridN = (int)gridDim.x, gridM = (int)gridDim.y;
    const int bid = (int)blockIdx.y * gridN + (int)blockIdx.x;
    const int GM = 8;
    const int per = GM * gridN;
    const int grp = bid / per;
    const int rem = bid - grp * per;
    const int gsz0 = gridM - grp * GM;
    const int gsz = gsz0 < GM ? gsz0 : GM;
    const int m0 = (grp * GM + rem % gsz) * 128;
    const int n0 = (rem / gsz) * 128;

    const int wv = tid >> 6;
    const int wm = (wv >> 1) * 64;
    const int wn = (wv & 1) * 64;

    f32x4 acc[4][4];
#pragma unroll
    for (int i = 0; i < 4; i++)
#pragma unroll
        for (int j = 0; j < 4; j++) acc[i][j] = (f32x4)0.f;

    for (int k0 = 0; k0 < K; k0 += 32) {
        __syncthreads();
#pragma unroll
        for (int is = 0; is < 2; ++is) {
            int c = is * 256 + tid;
            int row = c >> 2, col = (c & 3) * 8;
            llds16(A + (size_t)(m0 + row) * K + k0 + col, &As[c * 8]);
            llds16(B + (size_t)(n0 + row) * K + k0 + col, &Bs[c * 8]);
        }
        __syncthreads();
        short8 af[4], bf[4];
#pragma unroll
        for (int t = 0; t < 4; t++) {
            af[t] = *(const short8*)&As[(wm + t * 16 + (lane & 15)) * 32 + (lane >> 4) * 8];
            bf[t] = *(const short8*)&Bs[(wn + t * 16 + (lane & 15)) * 32 + (lane >> 4) * 8];
        }
#pragma unroll
        for (int i = 0; i < 4; i++)
#pragma unroll
            for (int j = 0; j < 4; j++)
                acc[i][j] = __builtin_amdgcn_mfma_f32_16x16x32_bf16(af[i], bf[j], acc[i][j], 0, 0, 0);
    }

    const int cr = (lane >> 4) * 4;
    const int cc = lane & 15;
    if constexpr (OUTMODE == 0) {
        unsigned short* o = (unsigned short*)outp;
#pragma unroll
        for (int i = 0; i < 4; i++)
#pragma unroll
            for (int j = 0; j < 4; j++) {
                int col = n0 + wn + j * 16 + cc;
#pragma unroll
                for (int r = 0; r < 4; r++) {
                    int row = m0 + wm + i * 16 + cr + r;
                    o[(size_t)row * N + col] = f2b(acc[i][j][r]);
                }
            }
    } else {
        float* o = (float*)outp;
#pragma unroll
        for (int j = 0; j < 4; j++) {
            int col = n0 + wn + j * 16 + cc;
            if (col < ncols) {
                float bv = bias[col];
#pragma unroll
                for (int i = 0; i < 4; i++)
#pragma unroll
                    for (int r = 0; r < 4; r++) {
                        int row = m0 + wm + i * 16 + cr + r;
                        o[(size_t)row * ncols + col] = acc[i][j][r] + bv;
                    }
            }
        }
    }
}

// ---------------- recurrent GEMM 1: [hp | gh] = h @ [W_h2h;W_hh]^T + bias ----------
// Direct-from-global MFMA fragments (no LDS, no barriers). Wave tile 16x32.
// grid (2048/128, 256/16) = (16,16), 256 thr = 4 waves.
__global__ __launch_bounds__(256) void gemm_hg(
    const unsigned short* __restrict__ h16, const unsigned short* __restrict__ w1,
    const float* __restrict__ b_h2h, const float* __restrict__ b_hh,
    float* __restrict__ hp, float* __restrict__ gh)
{
    const int tid = threadIdx.x, lane = tid & 63, wv = tid >> 6;
    const int m0 = blockIdx.y * 16;
    const int n0 = blockIdx.x * 128 + wv * 32;
    const unsigned short* ap = h16 + (size_t)(m0 + (lane & 15)) * H_ + (lane >> 4) * 8;
    const unsigned short* bp = w1 + (size_t)(n0 + (lane & 15)) * H_ + (lane >> 4) * 8;
    f32x4 acc0 = (f32x4)0.f, acc1 = (f32x4)0.f;
#pragma unroll
    for (int k0 = 0; k0 < H_; k0 += 32) {
        short8 a  = *(const short8*)(ap + k0);
        short8 b0 = *(const short8*)(bp + k0);
        short8 b1 = *(const short8*)(bp + (size_t)16 * H_ + k0);
        acc0 = __builtin_amdgcn_mfma_f32_16x16x32_bf16(a, b0, acc0, 0, 0, 0);
        acc1 = __builtin_amdgcn_mfma_f32_16x16x32_bf16(a, b1, acc1, 0, 0, 0);
    }
    const int cc = lane & 15, cr = (lane >> 4) * 4;
#pragma unroll
    for (int j = 0; j < 2; j++) {
        int col = n0 + j * 16 + cc;
        f32x4 av = j ? acc1 : acc0;
        float bv = (col < H_) ? b_h2h[col] : b_hh[col - H_];
#pragma unroll
        for (int r = 0; r < 4; r++) {
            int row = m0 + cr + r;
            float v = av[r] + bv;
            if (col < H_) hp[(size_t)row * H_ + col] = v;
            else          gh[(size_t)row * 1536 + (col - H_)] = v;
        }
    }
}

// ---------------- fused attention: hp -> e -> softmax -> context (bf16) -----------
// One block per b, 1024 threads (16 waves).
__global__ __launch_bounds__(1024) void attn_fused(
    const unsigned short* __restrict__ fp, const unsigned short* __restrict__ feats16,
    const float* __restrict__ hp, const float* __restrict__ wscore,
    unsigned short* __restrict__ ctx16)
{
    const int b = blockIdx.x;
    const int tid = threadIdx.x, lane = tid & 63, wv = tid >> 6;
    __shared__ float se[T_];
    __shared__ float ctx4[4][C_];

    float hpr[8], wsr[8];
    {
        const float* hb = hp + b * H_ + lane * 8;
        const float* wb = wscore + lane * 8;
#pragma unroll
        for (int i = 0; i < 8; i++) { hpr[i] = hb[i]; wsr[i] = wb[i]; }
    }
#pragma unroll
    for (int i = 0; i < 8; i++) {           // 16 waves x 8 t = 128
        int t = wv * 8 + i;
        short8 v = *(const short8*)(fp + ((size_t)t * B_ + b) * H_ + lane * 8);
        float p = 0.f;
#pragma unroll
        for (int j = 0; j < 8; j++)
            p += wsr[j] * tanh_fast(b2f((unsigned short)v[j]) + hpr[j]);
#pragma unroll
        for (int off = 32; off > 0; off >>= 1) p += __shfl_xor(p, off, 64);
        if (lane == 0) se[t] = p;
    }
    __syncthreads();
    if (wv == 0) {
        float v0 = se[lane], v1 = se[lane + 64];
        float mx = fmaxf(v0, v1);
#pragma unroll
        for (int off = 32; off > 0; off >>= 1) mx = fmaxf(mx, __shfl_xor(mx, off, 64));
        float e0 = __expf(v0 - mx), e1 = __expf(v1 - mx);
        float s = e0 + e1;
#pragma unroll
        for (int off = 32; off > 0; off >>= 1) s += __shfl_xor(s, off, 64);
        float inv = 1.f / s;
        se[lane] = e0 * inv; se[lane + 64] = e1 * inv;
    }
    __syncthreads();
    // context: thread handles 2 adjacent c, quarter of the t-range
    const int c = (tid & 255) * 2;
    const int q = tid >> 8;                 // 0..3
    float a0 = 0.f, a1 = 0.f;
    const unsigned short* fb = feats16 + (size_t)b * C_ + c;
    for (int i = 0; i < 32; i++) {
        int t = q * 32 + i;
        float al = se[t];
        unsigned int u = *(const unsigned int*)(fb + (size_t)t * B_ * C_);
        a0 += al * b2f((unsigned short)(u & 0xffffu));
        a1 += al * b2f((unsigned short)(u >> 16));
    }
    ctx4[q][c] = a0; ctx4[q][c + 1] = a1;
    __syncthreads();
    if (tid < C_) {
        float s = ctx4[0][tid] + ctx4[1][tid] + ctx4[2][tid] + ctx4[3][tid];
        ctx16[(size_t)b * C_ + tid] = f2b(s);
    }
}

// ---------------- recurrent GEMM 2 + GRU gates fused -----------------------------
// gi = ctx @ W_ih^T (3 gate accumulators per tile), epilogue applies gates,
// writes h32/h16/outH. Wave tile 16x16x3gates. grid (512/64, 256/16) = (8,16).
__global__ __launch_bounds__(256) void gemm_gates(
    const unsigned short* __restrict__ ctx, const unsigned short* __restrict__ wih,
    const float* __restrict__ gh, const float* __restrict__ b_ih,
    const float* __restrict__ hin32, float* __restrict__ hout32,
    unsigned short* __restrict__ hout16, unsigned short* __restrict__ outH, int step)
{
    const int tid = threadIdx.x, lane = tid & 63, wv = tid >> 6;
    const int m0 = blockIdx.y * 16;
    const int n0 = blockIdx.x * 64 + wv * 16;
    const unsigned short* ap = ctx + (size_t)(m0 + (lane & 15)) * C_ + (lane >> 4) * 8;
    const unsigned short* bp = wih + (size_t)(n0 + (lane & 15)) * H_ + (lane >> 4) * 8;
    f32x4 ar = (f32x4)0.f, az = (f32x4)0.f, an = (f32x4)0.f;
#pragma unroll
    for (int k0 = 0; k0 < H_; k0 += 32) {
        short8 a  = *(const short8*)(ap + k0);
        short8 br = *(const short8*)(bp + k0);
        short8 bz = *(const short8*)(bp + (size_t)512 * H_ + k0);
        short8 bn = *(const short8*)(bp + (size_t)1024 * H_ + k0);
        ar = __builtin_amdgcn_mfma_f32_16x16x32_bf16(a, br, ar, 0, 0, 0);
        az = __builtin_amdgcn_mfma_f32_16x16x32_bf16(a, bz, az, 0, 0, 0);
        an = __builtin_amdgcn_mfma_f32_16x16x32_bf16(a, bn, an, 0, 0, 0);
    }
    const int cc = lane & 15, cr = (lane >> 4) * 4;
    const int col = n0 + cc;
    const float br_ = b_ih[col], bz_ = b_ih[512 + col], bn_ = b_ih[1024 + col];
#pragma unroll
    for (int r = 0; r < 4; r++) {
        int row = m0 + cr + r;
        float ghr = gh[(size_t)row * 1536 + col];
        float ghz = gh[(size_t)row * 1536 + 512 + col];
        float ghn = gh[(size_t)row * 1536 + 1024 + col];
        float hv  = hin32[(size_t)row * H_ + col];
        float rg = sigm(ar[r] + br_ + ghr);
        float zg = sigm(az[r] + bz_ + ghz);
        float ng = tanh_fast(an[r] + bn_ + rg * ghn);
        float hn = (1.f - zg) * ng + zg * hv;
        hout32[(size_t)row * H_ + col] = hn;
        unsigned short hb = f2b(hn);
        hout16[(size_t)row * H_ + col] = hb;
        outH[((size_t)row * L_ + step) * H_ + col] = hb;
    }
}

extern "C" void kernel_launch(void* const* d_in, const int* in_sizes, int n_in,
                              void* d_out, int out_size, void* d_ws, size_t ws_size,
                              hipStream_t stream)
{
    const float* feats   = (const float*)d_in[0];
    const float* W_i2h   = (const float*)d_in[2];
    const float* W_h2h   = (const float*)d_in[3];
    const float* b_h2h   = (const float*)d_in[4];
    const float* W_score = (const float*)d_in[5];
    const float* W_ih    = (const float*)d_in[6];
    const float* W_hh    = (const float*)d_in[7];
    const float* b_ih    = (const float*)d_in[8];
    const float* b_hh    = (const float*)d_in[9];
    const float* W_gen   = (const float*)d_in[10];
    const float* b_gen   = (const float*)d_in[11];

    char* ws = (char*)d_ws;
    size_t off = 0;
    auto alloc = [&](size_t bytes) {
        void* p = ws + off; off += (bytes + 255) & ~(size_t)255; return p;
    };
    unsigned short* feats16 = (unsigned short*)alloc((size_t)T_ * B_ * C_ * 2);
    unsigned short* fp16    = (unsigned short*)alloc((size_t)T_ * B_ * H_ * 2);
    unsigned short* wgen16  = (unsigned short*)alloc((size_t)NPAD * H_ * 2);
    unsigned short* wi2h16  = (unsigned short*)alloc((size_t)H_ * C_ * 2);
    unsigned short* w1_16   = (unsigned short*)alloc((size_t)2048 * 512 * 2);
    unsigned short* wih16   = (unsigned short*)alloc((size_t)1536 * 512 * 2);
    unsigned short* outH16  = (unsigned short*)alloc((size_t)B_ * L_ * H_ * 2);
    float* h32a = (float*)alloc((size_t)B_ * H_ * 4);
    float* h32b = (float*)alloc((size_t)B_ * H_ * 4);
    unsigned short* h16a = (unsigned short*)alloc((size_t)B_ * H_ * 2);
    unsigned short* h16b = (unsigned short*)alloc((size_t)B_ * H_ * 2);
    float* hp  = (float*)alloc((size_t)B_ * H_ * 4);
    float* gh  = (float*)alloc((size_t)B_ * 1536 * 4);
    unsigned short* ctx16 = (unsigned short*)alloc((size_t)B_ * C_ * 2);

    prep_kernel<<<dim3((T_ * B_ * C_) / 256), 256, 0, stream>>>(
        feats, W_i2h, W_gen, W_h2h, W_hh, W_ih,
        feats16, wi2h16, wgen16, w1_16, wih16, h32a, h16a);

    // feats_proj = feats @ W_i2h^T  -> bf16 [T*B, H]
    gemm_bt<0><<<dim3(H_ / 128, (T_ * B_) / 128), 256, 0, stream>>>(
        feats16, wi2h16, fp16, nullptr, T_ * B_, H_, C_, 0);

    for (int s = 0; s < L_; s++) {
        const float* hin32          = (s & 1) ? h32b : h32a;
        float* hout32               = (s & 1) ? h32a : h32b;
        const unsigned short* hin16 = (s & 1) ? h16b : h16a;
        unsigned short* hout16      = (s & 1) ? h16a : h16b;
        gemm_hg<<<dim3(16, 16), 256, 0, stream>>>(hin16, w1_16, b_h2h, b_hh, hp, gh);
        attn_fused<<<dim3(B_), 1024, 0, stream>>>(fp16, feats16, hp, W_score, ctx16);
        gemm_gates<<<dim3(8, 16), 256, 0, stream>>>(
            ctx16, wih16, gh, b_ih, hin32, hout32, hout16, outH16, s);
    }

    // probs = out_h @ W_gen^T + b_gen
    gemm_bt<1><<<dim3(NPAD / 128, (B_ * L_) / 128), 256, 0, stream>>>(
        outH16, wgen16, d_out, b_gen, B_ * L_, NPAD, H_, NCLS);
}